// Round 2
// baseline (373.256 us; speedup 1.0000x reference)
//
#include <hip/hip_runtime.h>
#include <math.h>

// Collapsed GNNAttention:
//   out[b,n] = sum_l x[b,l,n]*fc1_w[l] + fc1_b
//   g[b,n]   = lin_b + rB[b] + out[b,n]*rw48 + x_dist[n]*rw49
//              + mean_{edges dst=n}(lB[b] + out[b,src]*lw48 + x_dist[src]*lw49)
//   y[b,n]   = mask ? -1e8 : log_softmax_n(g[b,:])
// lB/rB = dot of [week_emb(34)|x_features(2)|x_embed(12)] with lin_{l,r}_w[0:48],
// precomputed per-b by gnn_prep into d_ws.

namespace {
constexpr int NNODE = 1000;
constexpr int LSTOP = 20;
constexpr int LBV   = 30;
constexpr int ESV   = 34;
constexpr int SESV  = 12;
constexpr int NFV   = 2;
}

__global__ __launch_bounds__(256) void gnn_prep(
    const int*   __restrict__ stops,      // B x 20
    const float* __restrict__ x_features, // B x 2
    const int*   __restrict__ x_week,     // B
    const float* __restrict__ stop_emb,   // 1000 x 12
    const float* __restrict__ week_emb,   // 7 x 34
    const float* __restrict__ lin_l_w,    // 50
    const float* __restrict__ lin_r_w,    // 50
    float*       __restrict__ pb,         // B x 2 : {lB, rB}
    int B)
{
  const int b = blockIdx.x * 256 + threadIdx.x;
  if (b >= B) return;
  float sl = 0.f, sr = 0.f;
  const int w = x_week[b];
  const float* wr = week_emb + w * ESV;
  #pragma unroll
  for (int k = 0; k < ESV; ++k) {
    const float v = wr[k];
    sl = fmaf(v, lin_l_w[k], sl);
    sr = fmaf(v, lin_r_w[k], sr);
  }
  #pragma unroll
  for (int k = 0; k < NFV; ++k) {
    const float v = x_features[b * NFV + k];
    sl = fmaf(v, lin_l_w[ESV + k], sl);
    sr = fmaf(v, lin_r_w[ESV + k], sr);
  }
  float emb[SESV];
  #pragma unroll
  for (int j = 0; j < SESV; ++j) emb[j] = 0.f;
  #pragma unroll
  for (int l = 0; l < LSTOP; ++l) {
    const int s = stops[b * LSTOP + l];
    const float4* row = reinterpret_cast<const float4*>(stop_emb + s * SESV); // 48B rows, 16B aligned
    const float4 r0 = row[0], r1 = row[1], r2 = row[2];
    emb[0] += r0.x; emb[1] += r0.y; emb[2]  += r0.z; emb[3]  += r0.w;
    emb[4] += r1.x; emb[5] += r1.y; emb[6]  += r1.z; emb[7]  += r1.w;
    emb[8] += r2.x; emb[9] += r2.y; emb[10] += r2.z; emb[11] += r2.w;
  }
  #pragma unroll
  for (int j = 0; j < SESV; ++j) {
    sl = fmaf(emb[j], lin_l_w[ESV + NFV + j], sl);
    sr = fmaf(emb[j], lin_r_w[ESV + NFV + j], sr);
  }
  pb[2 * b]     = sl;
  pb[2 * b + 1] = sr;
}

__global__ __launch_bounds__(256) void gnn_main(
    const int*   __restrict__ stops,
    const float* __restrict__ x,       // B x 30 x 1000
    const float* __restrict__ x_dist,  // 1000
    const int*   __restrict__ x_mask,  // B x 1000
    const float* __restrict__ fc1_w,   // 30
    const float* __restrict__ fc1_b,   // 1
    const float* __restrict__ lin_l_w, // 50
    const float* __restrict__ lin_r_w, // 50
    const float* __restrict__ lin_b,   // 1
    const float* __restrict__ pb,      // B x 2
    float*       __restrict__ out)     // B x 1000
{
  const int b = blockIdx.x;
  const int t = threadIdx.x;

  __shared__ float  outs[NNODE];
  __shared__ float  sacc[NNODE];
  __shared__ float  cnts[NNODE];
  __shared__ int    stops_s[LSTOP];
  __shared__ float  fc1w_s[LBV];
  __shared__ float2 wred_s[4];

  // zero edge accumulators + stage tiny inputs (single barrier)
  for (int i = t; i < NNODE; i += 256) { sacc[i] = 0.f; cnts[i] = 0.f; }
  if (t < LSTOP) stops_s[t] = stops[b * LSTOP + t];
  if (t < LBV)   fc1w_s[t]  = fc1_w[t];
  __syncthreads();

  // ---- dominant stream: out[b,n] over the 120KB x-row, chunked to cap VGPRs ----
  const float fb = fc1_b[0];
  float4 acc = make_float4(fb, fb, fb, fb);
  float4 xd4 = make_float4(0.f, 0.f, 0.f, 0.f);
  if (t < NNODE / 4) {
    xd4 = *reinterpret_cast<const float4*>(x_dist + 4 * t);
    const float* xb = x + (size_t)b * (LBV * NNODE) + 4 * t;
    #pragma unroll 1
    for (int lo = 0; lo < LBV; lo += 10) {
      float4 v[10];
      #pragma unroll
      for (int u = 0; u < 10; ++u)
        v[u] = *reinterpret_cast<const float4*>(xb + (size_t)(lo + u) * NNODE);
      #pragma unroll
      for (int u = 0; u < 10; ++u) {
        const float w = fc1w_s[lo + u];
        acc.x = fmaf(v[u].x, w, acc.x);
        acc.y = fmaf(v[u].y, w, acc.y);
        acc.z = fmaf(v[u].z, w, acc.z);
        acc.w = fmaf(v[u].w, w, acc.w);
      }
    }
    *reinterpret_cast<float4*>(&outs[4 * t]) = acc;  // LDS copy only for edge gather
  }
  __syncthreads();

  // ---- 19-edge segment accumulation ----
  if (t < LSTOP - 1) {
    const float lB   = pb[2 * b];
    const float lw48 = lin_l_w[48];
    const float lw49 = lin_l_w[49];
    const int src = stops_s[t];
    const int dst = stops_s[t + 1];
    const float m = fmaf(outs[src], lw48, fmaf(x_dist[src], lw49, lB));
    atomicAdd(&sacc[dst], m);
    atomicAdd(&cnts[dst], 1.f);
  }
  __syncthreads();

  // ---- g + fused (max,sumexp) reduction ----
  const float rB   = pb[2 * b + 1];
  const float rw48 = lin_r_w[48];
  const float rw49 = lin_r_w[49];
  const float base = lin_b[0] + rB;

  float g0 = 0.f, g1 = 0.f, g2 = 0.f, g3 = 0.f;
  int4 mk = make_int4(0, 0, 0, 0);
  float m = -1e30f, s = 0.f;
  if (t < NNODE / 4) {
    mk = *reinterpret_cast<const int4*>(x_mask + (size_t)b * NNODE + 4 * t);
    const int n = 4 * t;
    float c;
    c = cnts[n + 0]; g0 = fmaf(acc.x, rw48, fmaf(xd4.x, rw49, base)) + ((c > 0.f) ? sacc[n + 0] / c : 0.f);
    c = cnts[n + 1]; g1 = fmaf(acc.y, rw48, fmaf(xd4.y, rw49, base)) + ((c > 0.f) ? sacc[n + 1] / c : 0.f);
    c = cnts[n + 2]; g2 = fmaf(acc.z, rw48, fmaf(xd4.z, rw49, base)) + ((c > 0.f) ? sacc[n + 2] / c : 0.f);
    c = cnts[n + 3]; g3 = fmaf(acc.w, rw48, fmaf(xd4.w, rw49, base)) + ((c > 0.f) ? sacc[n + 3] / c : 0.f);
    m = fmaxf(fmaxf(g0, g1), fmaxf(g2, g3));
    s = __expf(g0 - m) + __expf(g1 - m) + __expf(g2 - m) + __expf(g3 - m);
  }
  #pragma unroll
  for (int off = 32; off > 0; off >>= 1) {
    const float mo = __shfl_xor(m, off);
    const float so = __shfl_xor(s, off);
    const float nm = fmaxf(m, mo);
    s = s * __expf(m - nm) + so * __expf(mo - nm);
    m = nm;
  }
  if ((t & 63) == 0) wred_s[t >> 6] = make_float2(m, s);
  __syncthreads();
  const float2 r0 = wred_s[0], r1 = wred_s[1], r2 = wred_s[2], r3 = wred_s[3];
  const float M = fmaxf(fmaxf(r0.x, r1.x), fmaxf(r2.x, r3.x));
  const float S = r0.y * __expf(r0.x - M) + r1.y * __expf(r1.x - M) +
                  r2.y * __expf(r2.x - M) + r3.y * __expf(r3.x - M);
  const float lse = M + __logf(S);

  if (t < NNODE / 4) {
    float4 o;
    o.x = mk.x ? -100000000.0f : (g0 - lse);
    o.y = mk.y ? -100000000.0f : (g1 - lse);
    o.z = mk.z ? -100000000.0f : (g2 - lse);
    o.w = mk.w ? -100000000.0f : (g3 - lse);
    *reinterpret_cast<float4*>(out + (size_t)b * NNODE + 4 * t) = o;
  }
}

extern "C" void kernel_launch(void* const* d_in, const int* in_sizes, int n_in,
                              void* d_out, int out_size, void* d_ws, size_t ws_size,
                              hipStream_t stream) {
  const int*   stops      = (const int*)  d_in[0];
  const float* x          = (const float*)d_in[1];
  const float* x_dist     = (const float*)d_in[2];
  const float* x_features = (const float*)d_in[3];
  const int*   x_week     = (const int*)  d_in[4];
  const int*   x_mask     = (const int*)  d_in[5];
  const float* stop_emb   = (const float*)d_in[6];
  const float* week_emb   = (const float*)d_in[7];
  const float* fc1_w      = (const float*)d_in[8];
  const float* fc1_b      = (const float*)d_in[9];
  const float* lin_l_w    = (const float*)d_in[10];
  const float* lin_r_w    = (const float*)d_in[11];
  const float* lin_b      = (const float*)d_in[12];
  float* out = (float*)d_out;

  const int B = in_sizes[4];  // x_week has B elements
  float* pb = (float*)d_ws;   // B x 2 scratch

  gnn_prep<<<(B + 255) / 256, 256, 0, stream>>>(
      stops, x_features, x_week, stop_emb, week_emb, lin_l_w, lin_r_w, pb, B);
  gnn_main<<<B, 256, 0, stream>>>(
      stops, x, x_dist, x_mask, fc1_w, fc1_b, lin_l_w, lin_r_w, lin_b, pb, out);
}